// Round 2
// baseline (12339.858 us; speedup 1.0000x reference)
//
#include <hip/hip_runtime.h>

typedef unsigned short u16;
typedef unsigned int   u32;
using short8  = __attribute__((ext_vector_type(8))) short;
using short4v = __attribute__((ext_vector_type(4))) short;
using f32x4   = __attribute__((ext_vector_type(4))) float;

#define N_USER 200000
#define N_NEWS 100000
#define N_SRCT 5000
#define N_FOLW 200000
#define E_POSTS 500000
#define E_PUB   100000
#define E_FOLL  1000000

__device__ __forceinline__ float bf2f(u16 h) {
  union { u32 u; float f; } v; v.u = ((u32)h) << 16; return v.f;
}
__device__ __forceinline__ u16 f2bf(float f) {
  union { float f; u32 u; } v; v.f = f;
  u32 r = v.u + 0x7FFFu + ((v.u >> 16) & 1u);
  return (u16)(r >> 16);
}

// ---------------- degree counting ----------------
__global__ void count_k(const int* __restrict__ idx, int n, int* __restrict__ cnt) {
  int i = blockIdx.x * 256 + threadIdx.x;
  if (i < n) atomicAdd(&cnt[idx[i]], 1);
}
__global__ void rsqrt_k(float* __restrict__ buf, int n) {
  int i = blockIdx.x * 256 + threadIdx.x;
  if (i < n) {
    int c = ((const int*)buf)[i];
    buf[i] = rsqrtf((float)(c > 0 ? c : 1));
  }
}

// ---------------- fp32 -> bf16 convert + K-pad (row-major) ----------------
__global__ void cvt_pad_k(const float* __restrict__ X, u16* __restrict__ P,
                          int Ksrc, int Kdst, int total) {
  int i = blockIdx.x * 256 + threadIdx.x;
  if (i >= total) return;
  int row = i / Kdst;
  int k = i - row * Kdst;
  P[i] = (k < Ksrc) ? f2bf(X[(size_t)row * Ksrc + k]) : (u16)0;
}

// ---- weight: fp32 [nmat][Ksrc][128] -> bf16 k-major [nmat][128][Kdst] (K-padded) ----
__global__ void trans_w_k(const float* __restrict__ W, u16* __restrict__ WT,
                          int Ksrc, int Kdst, int total) {
  int i = blockIdx.x * 256 + threadIdx.x;
  if (i >= total) return;
  int per = Kdst << 7;
  int m = i / per, rem = i - m * per;
  int n = rem / Kdst, k = rem - n * Kdst;
  WT[i] = (k < Ksrc) ? f2bf(W[(size_t)m * Ksrc * 128 + (size_t)k * 128 + n]) : (u16)0;
}

// ---------------- MFMA GEMM: C[M,128] = act((A[M,K] @ W) * rowscale + bias) ----------------
// A bf16 [M,lda]; WT bf16 128 x K (k-major); K multiple of 32 (padded).
// Block: 256 thr = 4 waves, 128 rows/block, 32 rows/wave.
__global__ __launch_bounds__(256, 2) void gemm_bf16(
    const u16* __restrict__ A, int lda, int M, int K,
    const u16* __restrict__ WT,
    const float* __restrict__ bias,     // 128 fp32 or null
    const float* __restrict__ rowscale, // M fp32 or null
    u16* __restrict__ C, int leaky)
{
  __shared__ u16 Ws[128][136];   // [n][k-chunk], +8 pad
  const int tid  = threadIdx.x;
  const int wave = tid >> 6;
  const int lane = tid & 63;
  const int l15  = lane & 15;
  const int l4   = lane >> 4;
  const int rowBase = blockIdx.x * 128 + wave * 32;

  f32x4 acc[2][8];
#pragma unroll
  for (int g = 0; g < 2; ++g)
#pragma unroll
    for (int c = 0; c < 8; ++c) acc[g][c] = (f32x4){0.f, 0.f, 0.f, 0.f};

  const int r0 = (rowBase + l15 < M) ? rowBase + l15 : M - 1;
  const int r1 = (rowBase + 16 + l15 < M) ? rowBase + 16 + l15 : M - 1;

  for (int kb = 0; kb < K; kb += 128) {
    const int chunkK = (K - kb < 128) ? (K - kb) : 128;
    __syncthreads();
    for (int fl = tid * 8; fl < (chunkK << 7); fl += 2048) {
      int n = fl / chunkK;
      int kk = fl - n * chunkK;
      *(short8*)(&Ws[n][kk]) = *(const short8*)(WT + (size_t)n * K + kb + kk);
    }
    __syncthreads();
    const int nsteps = chunkK >> 5;
    for (int ks = 0; ks < nsteps; ++ks) {
      const int kg = ks * 32 + l4 * 8;
      short8 a0 = *(const short8*)(A + (size_t)r0 * lda + kb + kg);
      short8 a1 = *(const short8*)(A + (size_t)r1 * lda + kb + kg);
#pragma unroll
      for (int c = 0; c < 8; ++c) {
        short8 b = *(const short8*)(&Ws[c * 16 + l15][kg]);
        acc[0][c] = __builtin_amdgcn_mfma_f32_16x16x32_bf16(a0, b, acc[0][c], 0, 0, 0);
        acc[1][c] = __builtin_amdgcn_mfma_f32_16x16x32_bf16(a1, b, acc[1][c], 0, 0, 0);
      }
    }
  }

  float bvals[8];
#pragma unroll
  for (int c = 0; c < 8; ++c) bvals[c] = bias ? bias[c * 16 + l15] : 0.f;

#pragma unroll
  for (int g = 0; g < 2; ++g) {
#pragma unroll
    for (int r = 0; r < 4; ++r) {
      int row = rowBase + g * 16 + l4 * 4 + r;
      if (row >= M) continue;
      float sc = rowscale ? rowscale[row] : 1.f;
#pragma unroll
      for (int c = 0; c < 8; ++c) {
        float v = acc[g][c][r] * sc + bvals[c];
        if (leaky) v = (v > 0.f) ? v : 0.01f * v;
        C[(size_t)row * 128 + c * 16 + l15] = f2bf(v);
      }
    }
  }
}

// ---------------- edge scatter: ACC[dst] += T[src] * rsqrt(deg_in[dst]) ----------------
__global__ __launch_bounds__(256) void scatter_add(
    const u16* __restrict__ T, const int* __restrict__ src,
    const int* __restrict__ dst, const float* __restrict__ rsin,
    float* __restrict__ ACC, int E)
{
  int e = blockIdx.x * 8 + (threadIdx.x >> 5);
  if (e >= E) return;
  int l = threadIdx.x & 31;
  int s = src[e], d = dst[e];
  float sc = rsin[d];
  const u16* tp = T + ((size_t)s << 7) + l * 4;
  float* ap = ACC + ((size_t)d << 7) + l * 4;
  short4v t4 = *(const short4v*)tp;
#pragma unroll
  for (int j = 0; j < 4; ++j) atomicAdd(ap + j, bf2f((u16)t4[j]) * sc);
}

// ------- conv finalize: lrelu((ACC + sum_b) * invn) -> bf16 (HA) or fp32 (d_out) -------
__global__ void finalize_k(const float* __restrict__ ACC, const float* __restrict__ b1,
                           const float* __restrict__ b2, float invn,
                           u16* __restrict__ out_bf, float* __restrict__ out_f, int total)
{
  int i = (blockIdx.x * 256 + threadIdx.x) * 4;
  if (i >= total) return;
  int col = i & 127;
  f32x4 a = *(const f32x4*)(ACC + i);
  f32x4 vf;
#pragma unroll
  for (int j = 0; j < 4; ++j) {
    float bsum = b1[col + j] + (b2 ? b2[col + j] : 0.f);
    float v = (a[j] + bsum) * invn;
    vf[j] = (v > 0.f) ? v : 0.01f * v;
  }
  if (out_f) {
    *(f32x4*)(out_f + i) = vf;
  } else {
    short4v o;
#pragma unroll
    for (int j = 0; j < 4; ++j) o[j] = (short)f2bf(vf[j]);
    *(short4v*)(out_bf + i) = o;
  }
}

// ---------------- final linear: [rows,128] @ [128,2] + b (all fp32) ----------------
__global__ __launch_bounds__(256) void linear_k(
    const float* __restrict__ H, const float* __restrict__ Wl,
    const float* __restrict__ bl, float* __restrict__ OUT, int rows)
{
  __shared__ float w0[128], w1[128];
  int tid = threadIdx.x;
  if (tid < 128) { w0[tid] = Wl[tid * 2]; w1[tid] = Wl[tid * 2 + 1]; }
  __syncthreads();
  int row = blockIdx.x * 256 + tid;
  if (row >= rows) return;
  const float* hp = H + ((size_t)row << 7);
  float s0 = 0.f, s1 = 0.f;
#pragma unroll
  for (int k = 0; k < 128; k += 4) {
    f32x4 h4 = *(const f32x4*)(hp + k);
#pragma unroll
    for (int j = 0; j < 4; ++j) {
      s0 += h4[j] * w0[k + j];
      s1 += h4[j] * w1[k + j];
    }
  }
  OUT[(size_t)row * 2]     = s0 + bl[0];
  OUT[(size_t)row * 2 + 1] = s1 + bl[1];
}

extern "C" void kernel_launch(void* const* d_in, const int* in_sizes, int n_in,
                              void* d_out, int out_size, void* d_ws, size_t ws_size,
                              hipStream_t stream)
{
  (void)in_sizes; (void)n_in; (void)out_size; (void)ws_size;

  // ---- workspace carve-up ----
  char* wp = (char*)d_ws;
  auto take = [&](size_t bytes) { void* p = wp; wp += (bytes + 255) & ~(size_t)255; return p; };
  float* ACC = (float*)take(258560000); // 505000*128 f32; ALSO aliased as XB (bf16 inputs) pre-conv
  u16*   HA  = (u16*)take(129280000);   // 505000*128 bf16
  u16*   HB  = (u16*)take(129280000);
  u16*   T   = (u16*)take(51200000);    // 200000*128 bf16
  u16*   WTA = (u16*)take(1884160);     // transposed bf16 weights arena (942080 elems)
  float* CNT = (float*)take(3220000);   // 805000 f32 (int during counting)
  u16*   XB  = (u16*)ACC;               // bf16 input arena (83,840,000 elems) — dead before ACC use

  const int rowOff[4] = {0, 200000, 300000, 305000};   // user,news,source,follower
  const int Nt[4]     = {N_USER, N_NEWS, N_SRCT, N_FOLW};
  const size_t XOFF[4] = {0, 25600000, 57600000, 58240000};
  const int KD[4] = {128, 320, 128, 128};              // padded K per type
  const int KS[4] = {128, 300, 128, 128};
  const int WT1[4] = {0, 16384, 57344, 73728};
  const int WT2 = 90112, WTC1 = 155648, WTC2 = 548864;

  // ---- degrees ----
  hipMemsetAsync(CNT, 0, 805000 * 4, stream);
  auto countL = [&](int idx, int n, int off) {
    count_k<<<(n + 255) / 256, 256, 0, stream>>>((const int*)d_in[idx], n, ((int*)CNT) + off);
  };
  countL(26, E_POSTS, 0);       // deg(user) via posts_u
  countL(27, E_POSTS, 200000);  // deg(news) via posts_n
  countL(28, E_PUB,   300000);  // deg(source) via pub_s
  countL(29, E_PUB,   305000);  // deg(news) via pub_n
  countL(30, E_FOLL,  405000);  // deg(follower) via fol_f
  countL(31, E_FOLL,  605000);  // deg(user) via fol_u
  rsqrt_k<<<(805000 + 255) / 256, 256, 0, stream>>>(CNT, 805000);

  // ---- convert inputs fp32->bf16 (+pad news K 300->320) into XB ----
  for (int t = 0; t < 4; ++t) {
    int total = Nt[t] * KD[t];
    cvt_pad_k<<<(total + 255) / 256, 256, 0, stream>>>(
        (const float*)d_in[t], XB + XOFF[t], KS[t], KD[t], total);
  }
  // ---- weights fp32 -> bf16 k-major (+pad news Wi1) ----
  auto transL = [&](int idx, int wtOff, int Ksrc, int Kdst, int total) {
    trans_w_k<<<(total + 255) / 256, 256, 0, stream>>>(
        (const float*)d_in[idx], WTA + wtOff, Ksrc, Kdst, total);
  };
  transL(4,  WT1[0], 128, 128, 16384);
  transL(6,  WT1[1], 300, 320, 40960);
  transL(8,  WT1[2], 128, 128, 16384);
  transL(10, WT1[3], 128, 128, 16384);
  transL(12, WT2,    128, 128, 65536);    // Wi2 (4 mats)
  transL(14, WTC1,   128, 128, 393216);   // conv1_W (24 mats)
  transL(16, WTC2,   128, 128, 393216);   // conv2_W (24 mats)

  auto gemmL = [&](const u16* A, int lda, int M, int K, const u16* WTp,
                   const float* bias, const float* rs, u16* C, int leaky) {
    gemm_bf16<<<(M + 127) / 128, 256, 0, stream>>>(A, lda, M, K, WTp, bias, rs, C, leaky);
  };

  // ---- stage1: h = lrelu(x @ Wi1 + bi1) -> HA ----
  for (int t = 0; t < 4; ++t)
    gemmL(XB + XOFF[t], KD[t], Nt[t], KD[t], WTA + WT1[t],
          (const float*)d_in[5 + 2 * t], nullptr, HA + (size_t)rowOff[t] * 128, 1);

  // ---- stage2: h = lrelu(h @ Wi2 + bi2) -> HB ----
  for (int t = 0; t < 4; ++t)
    gemmL(HA + (size_t)rowOff[t] * 128, 128, Nt[t], 128, WTA + WT2 + t * 16384,
          (const float*)d_in[13] + t * 128, nullptr, HB + (size_t)rowOff[t] * 128, 1);

  // relation table
  struct RelH { int E, srcIdx, dstIdx, srcType, dstType, srcCnt, dstCnt; };
  const RelH rels[6] = {
    {E_POSTS, 26, 27, 0, 1, 0,      200000},  // posts: user->news
    {E_POSTS, 27, 26, 1, 0, 200000, 0},       // posted_by: news->user
    {E_PUB,   28, 29, 2, 1, 300000, 305000},  // publishes: source->news
    {E_PUB,   29, 28, 1, 2, 305000, 300000},  // published_by: news->source
    {E_FOLL,  30, 31, 3, 0, 405000, 605000},  // follows: follower->user
    {E_FOLL,  31, 30, 0, 3, 605000, 405000},  // followed_by: user->follower
  };
  const size_t H1OFF[4] = {1010000, 26610000, 39410000, 40050000};
  const size_t LOFF[4]  = {0, 400000, 600000, 610000};
  const int relsOf[4][2] = {{1, 4}, {0, 2}, {3, -1}, {5, -1}};
  float* OUT = (float*)d_out;

  // ---- conv layers (XB dead from here; ACC takes over the aliased region) ----
  for (int layer = 0; layer < 2; ++layer) {
    const u16* HIn     = layer ? HA : HB;
    const u16* wt      = WTA + (layer ? WTC2 : WTC1);
    const float* convb = (const float*)d_in[layer ? 17 : 15];
    hipMemsetAsync(ACC, 0, 258560000, stream);
    for (int r = 0; r < 6; ++r) {
      const RelH& q = rels[r];
      // T = (h_src @ W[dstType][r]) * rsqrt(deg_out)  (row-scale commutes with @W)
      gemmL(HIn + (size_t)rowOff[q.srcType] * 128, 128, Nt[q.srcType], 128,
            wt + (size_t)(q.dstType * 6 + r) * 16384, nullptr, CNT + q.srcCnt, T, 0);
      scatter_add<<<(q.E + 7) / 8, 256, 0, stream>>>(
          T, (const int*)d_in[q.srcIdx], (const int*)d_in[q.dstIdx],
          CNT + q.dstCnt, ACC + (size_t)rowOff[q.dstType] * 128, q.E);
    }
    for (int k = 0; k < 4; ++k) {
      int r1 = relsOf[k][0], r2 = relsOf[k][1];
      const float* b1 = convb + (size_t)(k * 6 + r1) * 128;
      const float* b2 = (r2 >= 0) ? convb + (size_t)(k * 6 + r2) * 128 : nullptr;
      float invn = (r2 >= 0) ? 0.5f : 1.0f;
      int total = Nt[k] * 128;
      u16* obf  = layer ? nullptr : (HA + (size_t)rowOff[k] * 128);
      float* of = layer ? (OUT + H1OFF[k]) : nullptr;
      finalize_k<<<(total / 4 + 255) / 256, 256, 0, stream>>>(
          ACC + (size_t)rowOff[k] * 128, b1, b2, invn, obf, of, total);
    }
  }

  // ---- final linear: logits = h1 @ Wl + bl ----
  for (int k = 0; k < 4; ++k)
    linear_k<<<(Nt[k] + 255) / 256, 256, 0, stream>>>(
        OUT + H1OFF[k], (const float*)d_in[18 + 2 * k], (const float*)d_in[19 + 2 * k],
        OUT + LOFF[k], Nt[k]);
}